// Round 2
// baseline (27343.805 us; speedup 1.0000x reference)
//
#include <hip/hip_runtime.h>
#include <hip/hip_bf16.h>
#include <stdint.h>

// ---------------- types / helpers ----------------
typedef __bf16 bf16x8 __attribute__((ext_vector_type(8)));
typedef __bf16 bf16x4 __attribute__((ext_vector_type(4)));
typedef float  f32x4  __attribute__((ext_vector_type(4)));

#define MFMA_B16(A_,B_,C_) __builtin_amdgcn_mfma_f32_16x16x32_bf16((A_),(B_),(C_),0,0,0)

static constexpr int TT = 200;   // time steps

static __device__ __forceinline__ float sig_f(float x){ return 1.f/(1.f+__expf(-x)); }
static __device__ __forceinline__ float tanh_f(float x){
  float e = __expf(-2.f*fabsf(x));
  float t = (1.f-e)/(1.f+e);
  return x<0.f ? -t : t;
}
static __device__ __forceinline__ float bf2f(unsigned short u){
  union{unsigned int i; float f;} v; v.i = ((unsigned)u)<<16; return v.f;
}

// XOR-swizzled LDS addressing (row-major tile read 16B/lane down a column is a
// bank conflict; byte ^= (row&7)<<4 spreads 8 rows over 128B -> conflict-free).
static __device__ __forceinline__ int swz_off(int row, int col_bytes, int strideB){
  return (row*strideB + col_bytes) ^ ((row&7)<<4);
}
static __device__ __forceinline__ bf16x8 lds_rdA(const __bf16* buf, int row, int kt, int lq, int strideB){
  int off = swz_off(row, kt*64 + lq*16, strideB);
  return *(const bf16x8*)((const char*)buf + off);
}
static __device__ __forceinline__ void lds_wr(__bf16* buf, int row, int dim, int strideB, float v){
  int off = swz_off(row, dim*2, strideB);
  *(__bf16*)((char*)buf + off) = (__bf16)v;
}

// ---------------- K0: f32 -> bf16 weight conversion ----------------
__global__ void cvt_bf16(const float* __restrict__ s, __bf16* __restrict__ d, int n){
  int i = blockIdx.x*blockDim.x + threadIdx.x;
  int st = gridDim.x*blockDim.x;
  for(; i<n; i+=st) d[i] = (__bf16)s[i];
}

// ---------------- K1: encoder scans, WAVE-LOCAL (no barriers in T-loop) -----
// grid (32,4): x = 16-row batch tile, y = cell {0:gf,1:gb,2:cf,3:cb}
// 64 threads = 1 wave owns 16 rows x all 256 hidden dims.
struct EncArgs {
  const float* x;               // [512][200][256] f32
  const __bf16* wih[4];         // [768][256]
  const __bf16* whh[4];         // [768][256]
  const float* bih[4];
  const float* bhh[4];
  __bf16* henc;                 // [200][512][512]
  float*  hencg;                // [512][512]
};

__global__ __launch_bounds__(64,1) void enc_w(EncArgs Ae){
  const int l = threadIdx.x, lr = l&15, lq = l>>4;
  const int cell = blockIdx.y;
  const bool fwd = (cell==0)||(cell==2);
  const bool isC = cell>=2;
  const int b0 = blockIdx.x*16;
  const __bf16* __restrict__ Wi = Ae.wih[cell];
  const __bf16* __restrict__ Wh = Ae.whh[cell];

  __shared__ __align__(16) __bf16 hA[16*256];   // h in A-frag layout (swizzled)
  __shared__ float blds[4*256];

  for(int i=l;i<16*256;i+=64) hA[i] = (__bf16)0.f;
  for(int d=l; d<256; d+=64){
    blds[d]     = Ae.bih[cell][d]     + Ae.bhh[cell][d];
    blds[256+d] = Ae.bih[cell][256+d] + Ae.bhh[cell][256+d];
    blds[512+d] = Ae.bih[cell][512+d];
    blds[768+d] = Ae.bhh[cell][512+d];
  }
  __syncthreads();   // prologue only

  f32x4 hC[16];
  #pragma unroll
  for(int i=0;i<16;i++) hC[i]=(f32x4){};

  const float* xbase = Ae.x + (size_t)(b0+lr)*TT*256 + lq*8;

  // prefetch x for step 0
  float4 xN[16];
  { const int tx0 = fwd ? 0 : TT-1;
    #pragma unroll
    for(int kt=0;kt<8;kt++){
      xN[2*kt]   = *(const float4*)(xbase + (size_t)tx0*256 + kt*32);
      xN[2*kt+1] = *(const float4*)(xbase + (size_t)tx0*256 + kt*32 + 4);
    }
  }

  #pragma unroll 1
  for(int s=0;s<TT;s++){
    const int tx = fwd ? s : TT-1-s;
    // convert prefetched x to bf16 A-frags
    bf16x8 xA[8];
    #pragma unroll
    for(int kt=0;kt<8;kt++){
      float4 a=xN[2*kt], b=xN[2*kt+1];
      bf16x8 v;
      v[0]=(__bf16)a.x; v[1]=(__bf16)a.y; v[2]=(__bf16)a.z; v[3]=(__bf16)a.w;
      v[4]=(__bf16)b.x; v[5]=(__bf16)b.y; v[6]=(__bf16)b.z; v[7]=(__bf16)b.w;
      xA[kt]=v;
    }
    // issue prefetch for next step (hides HBM latency under this step's MFMAs)
    if(s+1<TT){
      const int txn = fwd ? s+1 : TT-2-s;
      #pragma unroll
      for(int kt=0;kt<8;kt++){
        xN[2*kt]   = *(const float4*)(xbase + (size_t)txn*256 + kt*32);
        xN[2*kt+1] = *(const float4*)(xbase + (size_t)txn*256 + kt*32 + 4);
      }
    }
    // h A-frags (reads previous step's writes; same wave -> lgkmcnt only)
    bf16x8 hf[8];
    #pragma unroll
    for(int kt=0;kt<8;kt++) hf[kt] = lds_rdA(hA, lr, kt, lq, 512);

    #pragma unroll 2
    for(int dt=0;dt<16;dt++){
      const int d = dt*16+lr;
      f32x4 aR={}, aZ={}, aI={}, aH={};
      const __bf16* wiR = Wi + (size_t)d*256        + lq*8;
      const __bf16* wiZ = Wi + (size_t)(256+d)*256  + lq*8;
      const __bf16* wiN = Wi + (size_t)(512+d)*256  + lq*8;
      const __bf16* whR = Wh + (size_t)d*256        + lq*8;
      const __bf16* whZ = Wh + (size_t)(256+d)*256  + lq*8;
      const __bf16* whN = Wh + (size_t)(512+d)*256  + lq*8;
      #pragma unroll
      for(int kt=0;kt<8;kt++){
        aR = MFMA_B16(xA[kt], *(const bf16x8*)(wiR + kt*32), aR);
        aR = MFMA_B16(hf[kt], *(const bf16x8*)(whR + kt*32), aR);
        aZ = MFMA_B16(xA[kt], *(const bf16x8*)(wiZ + kt*32), aZ);
        aZ = MFMA_B16(hf[kt], *(const bf16x8*)(whZ + kt*32), aZ);
        aI = MFMA_B16(xA[kt], *(const bf16x8*)(wiN + kt*32), aI);
        aH = MFMA_B16(hf[kt], *(const bf16x8*)(whN + kt*32), aH);
      }
      const float bR=blds[d], bZ=blds[256+d], bI=blds[512+d], bH=blds[768+d];
      #pragma unroll
      for(int rr=0;rr<4;rr++){
        float r = sig_f(aR[rr]+bR);
        float z = sig_f(aZ[rr]+bZ);
        float nn= tanh_f(aI[rr]+bI + r*(aH[rr]+bH));
        float h = (1.f-z)*nn + z*hC[dt][rr];
        h = fminf(h, 5.f);
        hC[dt][rr] = h;
        lds_wr(hA, lq*4+rr, d, 512, h);
        if(isC)
          Ae.henc[((size_t)tx*512 + b0 + lq*4+rr)*512 + (cell==3?256:0) + d] = (__bf16)h;
      }
    }
  }
  if(!isC){
    #pragma unroll
    for(int dt=0;dt<16;dt++)
      #pragma unroll
      for(int rr=0;rr<4;rr++)
        Ae.hencg[(size_t)(b0+lq*4+rr)*512 + (cell==1?256:0) + dt*16+lr] = hC[dt][rr];
  }
}

// ---------------- K2: g0 head (f32 VALU) ----------------
__global__ void g0_kernel(const float* __restrict__ hencg,
                          const float* __restrict__ Wm, const float* __restrict__ bm,
                          const float* __restrict__ Wv, const float* __restrict__ bv,
                          const float* __restrict__ eps,
                          float* __restrict__ o_mean, float* __restrict__ o_logv,
                          float* __restrict__ g0){
  int j = blockIdx.x*blockDim.x + threadIdx.x;    // 512*256
  int b = j>>8, d = j&255;
  const float4* hp=(const float4*)(hencg + (size_t)b*512);
  const float4* mp=(const float4*)(Wm + (size_t)d*512);
  const float4* vp=(const float4*)(Wv + (size_t)d*512);
  float am=0.f, av=0.f;
  #pragma unroll 4
  for(int k=0;k<128;k++){
    float4 h=hp[k], m=mp[k], v=vp[k];
    am += h.x*m.x + h.y*m.y + h.z*m.z + h.w*m.w;
    av += h.x*v.x + h.y*v.y + h.z*v.z + h.w*v.w;
  }
  float mean = am + bm[d];
  float ev   = __expf(av + bv[d]) + 1e-4f;
  float lv   = __logf(ev);
  o_mean[j]=mean; o_logv[j]=lv;
  g0[j] = eps[j]*sqrtf(ev) + mean;
}

// ---------------- K3: gictT[t][384][512] = (h_enc_c @ Wct[:, :512]^T)^T -----
__global__ __launch_bounds__(256,2) void gict_gemm(const __bf16* __restrict__ henc,
                                                   const __bf16* __restrict__ wct,   // [384][576]
                                                   __bf16* __restrict__ gictT){
  const int tid=threadIdx.x, w=tid>>6, l=tid&63, lr=l&15, lq=l>>4;
  const int m0 = blockIdx.x*8 + w*2;
  bf16x8 a[2][16];
  #pragma unroll
  for(int m=0;m<2;m++){
    const __bf16* ap = henc + (size_t)((m0+m)*16 + lr)*512 + lq*8;
    #pragma unroll
    for(int kt=0;kt<16;kt++) a[m][kt] = *(const bf16x8*)(ap + kt*32);
  }
  #pragma unroll 1
  for(int nt=0;nt<24;nt++){
    f32x4 c0={}, c1={};
    const __bf16* bp = wct + (size_t)(nt*16+lr)*576 + lq*8;   // k in [0,512)
    #pragma unroll
    for(int kt=0;kt<16;kt++){
      bf16x8 bb = *(const bf16x8*)(bp + kt*32);
      c0 = MFMA_B16(a[0][kt], bb, c0);
      c1 = MFMA_B16(a[1][kt], bb, c1);
    }
    #pragma unroll
    for(int m=0;m<2;m++){
      f32x4 c = m? c1 : c0;
      int R0 = (m0+m)*16 + lq*4;                 // 4 consecutive flat rows
      int t  = R0>>9, b = R0&511;
      bf16x4 pk;
      pk[0]=(__bf16)c[0]; pk[1]=(__bf16)c[1]; pk[2]=(__bf16)c[2]; pk[3]=(__bf16)c[3];
      *(bf16x4*)(gictT + ((size_t)t*384 + nt*16+lr)*512 + b) = pk;  // 8B store
    }
  }
}

// ---------------- K4: generator scan, WAVE-LOCAL (no barriers in T-loop) ----
// 32 blocks x 64 threads; each wave owns 16 batch rows, all dims.
struct GenArgs{
  const __bf16 *wih_ct, *whh_ct, *wih_gn, *whh_gn, *w_um, *w_uv, *w_f;
  const float  *bih_ct, *bhh_ct, *bih_gn, *bhh_gn, *b_um, *b_uv, *b_f;
  const __bf16* gihT;   // [200][384][512]
  const float*  g0;     // [512][256]
  const float*  eps_u;  // [512][200][64]
  float *o_um, *o_ul, *o_f;
};

__global__ __launch_bounds__(64,1) void gen_w(GenArgs Ag){
  const int l = threadIdx.x, lr=l&15, lq=l>>4;
  const int b0 = blockIdx.x*16;

  __shared__ __align__(16) __bf16 hcA[16*128];   // 4KB
  __shared__ __align__(16) __bf16 uA [16*64];    // 2KB
  __shared__ __align__(16) __bf16 gA [16*256];   // 8KB
  __shared__ __align__(16) __bf16 fA [16*64];    // 2KB
  __shared__ float bct[4*128];
  __shared__ float bgn[4*256];

  for(int i=l;i<16*128;i+=64) hcA[i]=(__bf16)0.f;
  for(int d=l; d<128; d+=64){
    bct[d]     = Ag.bih_ct[d]     + Ag.bhh_ct[d];
    bct[128+d] = Ag.bih_ct[128+d] + Ag.bhh_ct[128+d];
    bct[256+d] = Ag.bih_ct[256+d];
    bct[384+d] = Ag.bhh_ct[256+d];
  }
  for(int d=l; d<256; d+=64){
    bgn[d]     = Ag.bih_gn[d]     + Ag.bhh_gn[d];
    bgn[256+d] = Ag.bih_gn[256+d] + Ag.bhh_gn[256+d];
    bgn[512+d] = Ag.bih_gn[512+d];
    bgn[768+d] = Ag.bhh_gn[512+d];
  }
  float bum[4], buvr[4], bfc[4];
  #pragma unroll
  for(int nt=0;nt<4;nt++){
    bum[nt]  = Ag.b_um[nt*16+lr];
    buvr[nt] = Ag.b_uv[nt*16+lr];
    bfc[nt]  = Ag.b_f[nt*16+lr];
  }

  // g carry (C-frag) + gA init
  f32x4 gC[16];
  #pragma unroll
  for(int dt=0;dt<16;dt++){
    #pragma unroll
    for(int rr=0;rr<4;rr++){
      float v = Ag.g0[(size_t)(b0+lq*4+rr)*256 + dt*16+lr];
      gC[dt][rr]=v;
      lds_wr(gA, lq*4+rr, dt*16+lr, 512, v);
    }
  }
  f32x4 hcC[8];
  #pragma unroll
  for(int i=0;i<8;i++) hcC[i]=(f32x4){};
  __syncthreads();   // prologue only

  // f0 = g0 @ W_f^T + b_f
  {
    bf16x8 gf[8];
    #pragma unroll
    for(int kt=0;kt<8;kt++) gf[kt] = lds_rdA(gA, lr, kt, lq, 512);
    #pragma unroll
    for(int nt=0;nt<4;nt++){
      f32x4 acc={};
      const __bf16* wp = Ag.w_f + (size_t)(nt*16+lr)*256 + lq*8;
      #pragma unroll
      for(int kt=0;kt<8;kt++) acc = MFMA_B16(gf[kt], *(const bf16x8*)(wp + kt*32), acc);
      #pragma unroll
      for(int rr=0;rr<4;rr++) lds_wr(fA, lq*4+rr, nt*16+lr, 128, acc[rr]+bfc[nt]);
    }
  }

  #pragma unroll 1
  for(int t=0;t<TT;t++){
    // ---- P1: controller GRU: h_c = GRU([henc(precomp), f], h_c) ----
    bf16x8 ff[2], hp[4];
    #pragma unroll
    for(int kt=0;kt<2;kt++) ff[kt] = lds_rdA(fA, lr, kt, lq, 128);
    #pragma unroll
    for(int kt=0;kt<4;kt++) hp[kt] = lds_rdA(hcA, lr, kt, lq, 256);
    #pragma unroll
    for(int dct=0;dct<8;dct++){
      const int d = dct*16+lr;
      // precomputed henc-part of gates, transposed layout -> one 8B load per gate
      ushort4 uR = *(const ushort4*)(Ag.gihT + ((size_t)t*384 +       d)*512 + b0 + lq*4);
      ushort4 uZ = *(const ushort4*)(Ag.gihT + ((size_t)t*384 + 128 + d)*512 + b0 + lq*4);
      ushort4 uN = *(const ushort4*)(Ag.gihT + ((size_t)t*384 + 256 + d)*512 + b0 + lq*4);
      f32x4 aR={}, aZ={}, aI={}, aH={};
      const __bf16* wiR = Ag.wih_ct + (size_t)(d      )*576 + 512 + lq*8;
      const __bf16* wiZ = Ag.wih_ct + (size_t)(128+d  )*576 + 512 + lq*8;
      const __bf16* wiN = Ag.wih_ct + (size_t)(256+d  )*576 + 512 + lq*8;
      const __bf16* whR = Ag.whh_ct + (size_t)(d      )*128 + lq*8;
      const __bf16* whZ = Ag.whh_ct + (size_t)(128+d  )*128 + lq*8;
      const __bf16* whN = Ag.whh_ct + (size_t)(256+d  )*128 + lq*8;
      #pragma unroll
      for(int kt=0;kt<2;kt++){
        aR = MFMA_B16(ff[kt], *(const bf16x8*)(wiR + kt*32), aR);
        aZ = MFMA_B16(ff[kt], *(const bf16x8*)(wiZ + kt*32), aZ);
        aI = MFMA_B16(ff[kt], *(const bf16x8*)(wiN + kt*32), aI);
      }
      #pragma unroll
      for(int kt=0;kt<4;kt++){
        aR = MFMA_B16(hp[kt], *(const bf16x8*)(whR + kt*32), aR);
        aZ = MFMA_B16(hp[kt], *(const bf16x8*)(whZ + kt*32), aZ);
        aH = MFMA_B16(hp[kt], *(const bf16x8*)(whN + kt*32), aH);
      }
      const float bR=bct[d], bZ=bct[128+d], bI=bct[256+d], bH=bct[384+d];
      const unsigned short* pR=(const unsigned short*)&uR;
      const unsigned short* pZ=(const unsigned short*)&uZ;
      const unsigned short* pN=(const unsigned short*)&uN;
      #pragma unroll
      for(int rr=0;rr<4;rr++){
        float r = sig_f(aR[rr] + bf2f(pR[rr]) + bR);
        float z = sig_f(aZ[rr] + bf2f(pZ[rr]) + bZ);
        float nn= tanh_f(aI[rr] + bf2f(pN[rr]) + bI + r*(aH[rr] + bH));
        float h = (1.f-z)*nn + z*hcC[dct][rr];
        h = fminf(fmaxf(h,0.f), 5.f);
        hcC[dct][rr]=h;
        lds_wr(hcA, lq*4+rr, d, 256, h);
      }
    }

    // ---- P2: um/uv + sample u ----
    {
      bf16x8 hn[4];
      #pragma unroll
      for(int kt=0;kt<4;kt++) hn[kt] = lds_rdA(hcA, lr, kt, lq, 256);
      #pragma unroll
      for(int nt=0;nt<4;nt++){
        const int d = nt*16+lr;
        f32x4 am={}, av={};
        const __bf16* wm = Ag.w_um + (size_t)d*128 + lq*8;
        const __bf16* wv = Ag.w_uv + (size_t)d*128 + lq*8;
        #pragma unroll
        for(int kt=0;kt<4;kt++){
          am = MFMA_B16(hn[kt], *(const bf16x8*)(wm + kt*32), am);
          av = MFMA_B16(hn[kt], *(const bf16x8*)(wv + kt*32), av);
        }
        #pragma unroll
        for(int rr=0;rr<4;rr++){
          const int row = lq*4+rr;
          float um = am[rr] + bum[nt];
          float ul = av[rr] + buvr[nt];
          size_t oi = ((size_t)(b0+row)*TT + t)*64 + d;
          Ag.o_um[oi] = um;
          Ag.o_ul[oi] = ul;
          float e = Ag.eps_u[oi];
          float u = e*__expf(0.5f*ul) + um;
          lds_wr(uA, row, d, 128, u);
        }
      }
    }

    // ---- P3: generator GRU: g = GRU(u, g) ----
    {
      bf16x8 uf[2], gf[8];
      #pragma unroll
      for(int kt=0;kt<2;kt++) uf[kt] = lds_rdA(uA, lr, kt, lq, 128);
      #pragma unroll
      for(int kt=0;kt<8;kt++) gf[kt] = lds_rdA(gA, lr, kt, lq, 512);
      #pragma unroll 2
      for(int dt=0;dt<16;dt++){
        const int d = dt*16+lr;
        f32x4 aR={}, aZ={}, aI={}, aH={};
        const __bf16* wiR = Ag.wih_gn + (size_t)(d      )*64 + lq*8;
        const __bf16* wiZ = Ag.wih_gn + (size_t)(256+d  )*64 + lq*8;
        const __bf16* wiN = Ag.wih_gn + (size_t)(512+d  )*64 + lq*8;
        const __bf16* whR = Ag.whh_gn + (size_t)(d      )*256 + lq*8;
        const __bf16* whZ = Ag.whh_gn + (size_t)(256+d  )*256 + lq*8;
        const __bf16* whN = Ag.whh_gn + (size_t)(512+d  )*256 + lq*8;
        #pragma unroll
        for(int kt=0;kt<2;kt++){
          aR = MFMA_B16(uf[kt], *(const bf16x8*)(wiR + kt*32), aR);
          aZ = MFMA_B16(uf[kt], *(const bf16x8*)(wiZ + kt*32), aZ);
          aI = MFMA_B16(uf[kt], *(const bf16x8*)(wiN + kt*32), aI);
        }
        #pragma unroll
        for(int kt=0;kt<8;kt++){
          aR = MFMA_B16(gf[kt], *(const bf16x8*)(whR + kt*32), aR);
          aZ = MFMA_B16(gf[kt], *(const bf16x8*)(whZ + kt*32), aZ);
          aH = MFMA_B16(gf[kt], *(const bf16x8*)(whN + kt*32), aH);
        }
        const float bR=bgn[d], bZ=bgn[256+d], bI=bgn[512+d], bH=bgn[768+d];
        #pragma unroll
        for(int rr=0;rr<4;rr++){
          float r = sig_f(aR[rr]+bR);
          float z = sig_f(aZ[rr]+bZ);
          float nn= tanh_f(aI[rr]+bI + r*(aH[rr]+bH));
          float gv = (1.f-z)*nn + z*gC[dt][rr];
          gv = fminf(fmaxf(gv,0.f), 5.f);
          gC[dt][rr]=gv;
          lds_wr(gA, lq*4+rr, d, 512, gv);
        }
      }
    }

    // ---- P4: f = g @ W_f^T + b_f ----
    {
      bf16x8 gf[8];
      #pragma unroll
      for(int kt=0;kt<8;kt++) gf[kt] = lds_rdA(gA, lr, kt, lq, 512);
      #pragma unroll
      for(int nt=0;nt<4;nt++){
        const int d = nt*16+lr;
        f32x4 acc={};
        const __bf16* wp = Ag.w_f + (size_t)d*256 + lq*8;
        #pragma unroll
        for(int kt=0;kt<8;kt++) acc = MFMA_B16(gf[kt], *(const bf16x8*)(wp + kt*32), acc);
        #pragma unroll
        for(int rr=0;rr<4;rr++){
          const int row = lq*4+rr;
          float v = acc[rr] + bfc[nt];
          Ag.o_f[((size_t)(b0+row)*TT + t)*64 + d] = v;
          lds_wr(fA, row, d, 128, v);
        }
      }
    }
  }
}

// ---------------- K5: rates = exp(clip(factors@W_r^T + b_r)) ----------------
__global__ void rates_k(const float* __restrict__ fac, const float* __restrict__ Wr,
                        const float* __restrict__ br, float* __restrict__ out){
  const int total = 512*200*256;
  int i = blockIdx.x*blockDim.x + threadIdx.x;
  int st = gridDim.x*blockDim.x;
  for(; i<total; i+=st){
    int row = i>>8, n = i&255;
    const float4* fp=(const float4*)(fac + (size_t)row*64);
    const float4* wp=(const float4*)(Wr  + (size_t)n*64);
    float a = 0.f;
    #pragma unroll
    for(int k=0;k<16;k++){
      float4 f=fp[k], ww=wp[k];
      a += f.x*ww.x + f.y*ww.y + f.z*ww.z + f.w*ww.w;
    }
    a += br[n];
    a = fminf(fmaxf(a, -5.f), 5.f);
    out[i] = __expf(a);
  }
}

// ---------------- host ----------------
extern "C" void kernel_launch(void* const* d_in, const int* in_sizes, int n_in,
                              void* d_out, int out_size, void* d_ws, size_t ws_size,
                              hipStream_t stream){
  (void)in_sizes; (void)n_in; (void)out_size; (void)ws_size;
  const float* x      = (const float*)d_in[0];
  const float* eps_g0 = (const float*)d_in[1];
  const float* eps_u  = (const float*)d_in[2];
  const float* Wih_f[6]; const float* Whh_f[6]; const float* bih[6]; const float* bhh[6];
  for(int c=0;c<6;c++){
    Wih_f[c]=(const float*)d_in[3+4*c]; Whh_f[c]=(const float*)d_in[4+4*c];
    bih[c]  =(const float*)d_in[5+4*c]; bhh[c]  =(const float*)d_in[6+4*c];
  }
  const float* W_g0m=(const float*)d_in[27]; const float* b_g0m=(const float*)d_in[28];
  const float* W_g0v=(const float*)d_in[29]; const float* b_g0v=(const float*)d_in[30];
  const float* W_um =(const float*)d_in[31]; const float* b_um =(const float*)d_in[32];
  const float* W_uv =(const float*)d_in[33]; const float* b_uv =(const float*)d_in[34];
  const float* W_f  =(const float*)d_in[35]; const float* b_f  =(const float*)d_in[36];
  const float* W_r  =(const float*)d_in[37]; const float* b_r  =(const float*)d_in[38];

  char* ws = (char*)d_ws; size_t off = 0;
  auto alloc = [&](size_t bytes)->char*{
    char* p = ws + off; off = (off + bytes + 255) & ~(size_t)255; return p;
  };
  static const int ih_sz[6] = {768*256,768*256,768*256,768*256,384*576,768*64};
  static const int hh_sz[6] = {768*256,768*256,768*256,768*256,384*128,768*256};
  __bf16* wih_b[6]; __bf16* whh_b[6];
  for(int c=0;c<6;c++){
    wih_b[c]=(__bf16*)alloc((size_t)ih_sz[c]*2);
    whh_b[c]=(__bf16*)alloc((size_t)hh_sz[c]*2);
  }
  __bf16* wum_b=(__bf16*)alloc(64*128*2);
  __bf16* wuv_b=(__bf16*)alloc(64*128*2);
  __bf16* wf_b =(__bf16*)alloc(64*256*2);
  __bf16* henc =(__bf16*)alloc((size_t)200*512*512*2);
  __bf16* gictT=(__bf16*)alloc((size_t)200*384*512*2);
  float*  hencg=(float*)alloc((size_t)512*512*4);
  float*  g0   =(float*)alloc((size_t)512*256*4);

  for(int c=0;c<6;c++){
    cvt_bf16<<<128,256,0,stream>>>(Wih_f[c], wih_b[c], ih_sz[c]);
    cvt_bf16<<<128,256,0,stream>>>(Whh_f[c], whh_b[c], hh_sz[c]);
  }
  cvt_bf16<<<32,256,0,stream>>>(W_um, wum_b, 64*128);
  cvt_bf16<<<32,256,0,stream>>>(W_uv, wuv_b, 64*128);
  cvt_bf16<<<32,256,0,stream>>>(W_f,  wf_b,  64*256);

  EncArgs ea;
  ea.x = x;
  for(int c=0;c<4;c++){ ea.wih[c]=wih_b[c]; ea.whh[c]=whh_b[c]; ea.bih[c]=bih[c]; ea.bhh[c]=bhh[c]; }
  ea.henc = henc; ea.hencg = hencg;
  enc_w<<<dim3(32,4),64,0,stream>>>(ea);

  float* out = (float*)d_out;
  float* o_mean = out;
  float* o_logv = out + 131072;
  float* o_um   = out + 262144;
  float* o_ul   = out + 6815744;
  float* o_f    = out + 13369344;
  float* o_r    = out + 19922944;

  g0_kernel<<<512,256,0,stream>>>(hencg, W_g0m,b_g0m, W_g0v,b_g0v, eps_g0, o_mean,o_logv, g0);
  gict_gemm<<<800,256,0,stream>>>(henc, wih_b[4], gictT);

  GenArgs ga;
  ga.wih_ct=wih_b[4]; ga.whh_ct=whh_b[4]; ga.wih_gn=wih_b[5]; ga.whh_gn=whh_b[5];
  ga.w_um=wum_b; ga.w_uv=wuv_b; ga.w_f=wf_b;
  ga.bih_ct=bih[4]; ga.bhh_ct=bhh[4]; ga.bih_gn=bih[5]; ga.bhh_gn=bhh[5];
  ga.b_um=b_um; ga.b_uv=b_uv; ga.b_f=b_f;
  ga.gihT=gictT; ga.g0=g0; ga.eps_u=eps_u;
  ga.o_um=o_um; ga.o_ul=o_ul; ga.o_f=o_f;
  gen_w<<<32,64,0,stream>>>(ga);

  rates_k<<<8192,256,0,stream>>>(o_f, W_r, b_r, o_r);
}

// Round 3
// 7137.050 us; speedup vs baseline: 3.8312x; 3.8312x over previous
//
#include <hip/hip_runtime.h>
#include <hip/hip_bf16.h>
#include <stdint.h>

typedef __bf16 bf16x8 __attribute__((ext_vector_type(8)));
typedef __bf16 bf16x4 __attribute__((ext_vector_type(4)));
typedef float  f32x4  __attribute__((ext_vector_type(4)));
typedef unsigned short u16x8 __attribute__((ext_vector_type(8)));

#define MFMA_B16(A_,B_,C_) __builtin_amdgcn_mfma_f32_16x16x32_bf16((A_),(B_),(C_),0,0,0)

static constexpr int TT = 200;
static constexpr int TC = 25;     // T-chunk for encoder
static constexpr int NCH = 8;     // chunks

static __device__ __forceinline__ float sig_f(float x){ return 1.f/(1.f+__expf(-x)); }
static __device__ __forceinline__ float tanh_f(float x){
  float e = __expf(-2.f*fabsf(x));
  float t = (1.f-e)/(1.f+e);
  return x<0.f ? -t : t;
}
static __device__ __forceinline__ float bf2f(unsigned short u){
  union{unsigned int i; float f;} v; v.i = ((unsigned)u)<<16; return v.f;
}
// swizzled LDS helpers (row-major tile, byte ^= (row&7)<<4)
static __device__ __forceinline__ int swz_off(int row, int col_bytes, int strideB){
  return (row*strideB + col_bytes) ^ ((row&7)<<4);
}
static __device__ __forceinline__ bf16x8 lds_rdA(const __bf16* buf, int row, int kt, int lq, int strideB){
  return *(const bf16x8*)((const char*)buf + swz_off(row, kt*64 + lq*16, strideB));
}
static __device__ __forceinline__ void lds_wr(__bf16* buf, int row, int dim, int strideB, float v){
  *(__bf16*)((char*)buf + swz_off(row, dim*2, strideB)) = (__bf16)v;
}
// lgkm-only barrier: LDS producer/consumer sync WITHOUT draining vmcnt
// (keeps global prefetch loads in flight across the barrier)
static __device__ __forceinline__ void lds_barrier(){
  asm volatile("s_waitcnt lgkmcnt(0)" ::: "memory");
  __builtin_amdgcn_s_barrier();
}

// ---------------- K0: f32 -> bf16 ----------------
__global__ void cvt_bf16(const float* __restrict__ s, __bf16* __restrict__ d, int n){
  int i = blockIdx.x*blockDim.x + threadIdx.x;
  int st = gridDim.x*blockDim.x;
  for(; i<n; i+=st) d[i] = (__bf16)s[i];
}

// ---------------- K1: gi GEMM (per chunk) ----------------
// gi[cell][tloc][768][512] = x(t_abs) @ Wih_cell^T, bf16.
// grid (chunk_m_tiles=200, 4 cells), block 256 (4 waves x 16 m-rows = 64 rows).
__global__ __launch_bounds__(256) void gi_gemm(const float* __restrict__ x,
                                               const __bf16* __restrict__ Wall, // [4*768][256]
                                               __bf16* __restrict__ gi, int t0){
  const int tid=threadIdx.x, w=tid>>6, l=tid&63, lr=l&15, lq=l>>4;
  const int cell = blockIdx.y;
  const bool fwd = (cell&1)==0;
  const int m0 = blockIdx.x*64;
  const int tloc = m0>>9, b0 = m0&511;
  const int tabs = fwd ? (t0+tloc) : (TT-1-(t0+tloc));
  const int brow = b0 + w*16 + lr;

  const float* xp = x + (size_t)brow*TT*256 + (size_t)tabs*256 + lq*8;
  bf16x8 a[8];
  #pragma unroll
  for(int kt=0;kt<8;kt++){
    float4 f0 = *(const float4*)(xp + kt*32);
    float4 f1 = *(const float4*)(xp + kt*32 + 4);
    bf16x8 v;
    v[0]=(__bf16)f0.x; v[1]=(__bf16)f0.y; v[2]=(__bf16)f0.z; v[3]=(__bf16)f0.w;
    v[4]=(__bf16)f1.x; v[5]=(__bf16)f1.y; v[6]=(__bf16)f1.z; v[7]=(__bf16)f1.w;
    a[kt]=v;
  }
  const __bf16* Wc = Wall + (size_t)cell*768*256;
  #pragma unroll 1
  for(int nt=0;nt<48;nt++){
    f32x4 acc={};
    const __bf16* bp = Wc + (size_t)(nt*16+lr)*256 + lq*8;
    #pragma unroll
    for(int kt=0;kt<8;kt++)
      acc = MFMA_B16(a[kt], *(const bf16x8*)(bp + kt*32), acc);
    bf16x4 pk;
    pk[0]=(__bf16)acc[0]; pk[1]=(__bf16)acc[1]; pk[2]=(__bf16)acc[2]; pk[3]=(__bf16)acc[3];
    *(bf16x4*)(gi + (((size_t)cell*TC + tloc)*768 + nt*16+lr)*512 + b0 + w*16 + lq*4) = pk;
  }
}

// ---------------- K2: encoder scan (persistent Whh in registers) ----------------
// grid (32 b-groups, 4 cells), block 512 (8 waves); wave w owns h-dims [w*32,w*32+32).
struct EncP{
  const __bf16* whh;            // [4][768][256]
  const float*  bih[4];
  const float*  bhh[4];
  const __bf16* gi;             // [4][TC][768][512]
  __bf16* henc;                 // [200][512][512]
  float*  hcar;                 // [4][512][256]
  int t0;
};
__global__ __launch_bounds__(512,2) void enc_scan(EncP P){
  const int tid=threadIdx.x, w=tid>>6, l=tid&63, lr=l&15, lq=l>>4;
  const int cell=blockIdx.y, b0=blockIdx.x*16;
  const bool fwd = (cell&1)==0;
  const bool isC = cell>=2;
  const int dim0 = w*32;

  __shared__ __align__(16) __bf16 hA[2][16*256];     // 2 x 8KB
  __shared__ __align__(16) __bf16 giL[2][768*16];    // 2 x 24KB
  __shared__ float blds[1024];

  for(int d=tid; d<256; d+=512){
    blds[d]     = P.bih[cell][d]     + P.bhh[cell][d];
    blds[256+d] = P.bih[cell][256+d] + P.bhh[cell][256+d];
    blds[512+d] = P.bih[cell][512+d];
    blds[768+d] = P.bhh[cell][512+d];
  }
  // persistent weights: Whh slice in 192 VGPRs
  bf16x8 wreg[2][3][8];
  {
    const __bf16* Wh = P.whh + (size_t)cell*768*256;
    #pragma unroll
    for(int jt=0;jt<2;jt++)
      #pragma unroll
      for(int g=0;g<3;g++)
        #pragma unroll
        for(int kt=0;kt<8;kt++)
          wreg[jt][g][kt] = *(const bf16x8*)(Wh + (size_t)(g*256 + dim0 + jt*16 + lr)*256 + kt*32 + lq*8);
  }
  // carry
  f32x4 hold[2];
  #pragma unroll
  for(int jt=0;jt<2;jt++)
    #pragma unroll
    for(int rr=0;rr<4;rr++){
      float v = P.hcar[((size_t)cell*512 + b0 + lq*4+rr)*256 + dim0 + jt*16 + lr];
      hold[jt][rr] = v;
      lds_wr(hA[0], lq*4+rr, dim0+jt*16+lr, 512, v);
    }
  // gi prefetch mapping: wave w stages per-cell gate-rows [w*96, w*96+96)
  const int prow = w*96 + (l>>1), phal = l&1;
  const __bf16* gbase = P.gi + ((size_t)cell*TC*768 + prow)*512 + b0 + phal*8;
  u16x8 pf0, pf1, pf2;
  pf0 = *(const u16x8*)(gbase + (size_t)0*768*512 +  0*512);
  pf1 = *(const u16x8*)(gbase + (size_t)0*768*512 + 32*512);
  pf2 = *(const u16x8*)(gbase + (size_t)0*768*512 + 64*512);
  __syncthreads();
  { // stage gi(0) into giL[0]
    __bf16* gl = giL[0] + prow*16 + phal*8;
    *(u16x8*)(gl)        = pf0;
    *(u16x8*)(gl+32*16)  = pf1;
    *(u16x8*)(gl+64*16)  = pf2;
  }
  { int sn = 1 < TC ? 1 : TC-1;
    pf0 = *(const u16x8*)(gbase + (size_t)sn*768*512 +  0*512);
    pf1 = *(const u16x8*)(gbase + (size_t)sn*768*512 + 32*512);
    pf2 = *(const u16x8*)(gbase + (size_t)sn*768*512 + 64*512);
  }
  lds_barrier();

  int p=0, q=0;
  #pragma unroll 1
  for(int s=0;s<TC;s++){
    const int tglob = P.t0 + s;
    const int tx = fwd ? tglob : (TT-1-tglob);
    // stage gi(s+1) into giL[1-q]
    if(s+1<TC){
      __bf16* gl = giL[1-q] + prow*16 + phal*8;
      *(u16x8*)(gl)        = pf0;
      *(u16x8*)(gl+32*16)  = pf1;
      *(u16x8*)(gl+64*16)  = pf2;
    }
    // issue prefetch for s+2
    { int sn = (s+2<TC) ? s+2 : TC-1;
      pf0 = *(const u16x8*)(gbase + (size_t)sn*768*512 +  0*512);
      pf1 = *(const u16x8*)(gbase + (size_t)sn*768*512 + 32*512);
      pf2 = *(const u16x8*)(gbase + (size_t)sn*768*512 + 64*512);
    }
    const __bf16* gq = giL[q];
    #pragma unroll
    for(int jt=0;jt<2;jt++){
      f32x4 aR={}, aZ={}, aH={};
      #pragma unroll
      for(int kt=0;kt<8;kt++){
        bf16x8 frag = lds_rdA(hA[p], lr, kt, lq, 512);
        aR = MFMA_B16(frag, wreg[jt][0][kt], aR);
        aZ = MFMA_B16(frag, wreg[jt][1][kt], aZ);
        aH = MFMA_B16(frag, wreg[jt][2][kt], aH);
      }
      const int d = dim0 + jt*16 + lr;
      ushort4 gR = *(const ushort4*)(gq + (0*256+d)*16 + lq*4);
      ushort4 gZ = *(const ushort4*)(gq + (1*256+d)*16 + lq*4);
      ushort4 gN = *(const ushort4*)(gq + (2*256+d)*16 + lq*4);
      const float bR=blds[d], bZ=blds[256+d], bI=blds[512+d], bH=blds[768+d];
      const unsigned short* uR=(const unsigned short*)&gR;
      const unsigned short* uZ=(const unsigned short*)&gZ;
      const unsigned short* uN=(const unsigned short*)&gN;
      #pragma unroll
      for(int rr=0;rr<4;rr++){
        float r = sig_f(aR[rr] + bf2f(uR[rr]) + bR);
        float z = sig_f(aZ[rr] + bf2f(uZ[rr]) + bZ);
        float nn= tanh_f(bf2f(uN[rr]) + bI + r*(aH[rr] + bH));
        float h = (1.f-z)*nn + z*hold[jt][rr];
        h = fminf(h, 5.f);
        hold[jt][rr] = h;
        lds_wr(hA[1-p], lq*4+rr, d, 512, h);
      }
    }
    if(isC){
      const int row = l>>2, dgrp = (l&3)*8;
      bf16x8 hv = *(const bf16x8*)((const char*)hA[1-p] +
                    ((row*512 + (dim0+dgrp)*2) ^ ((row&7)<<4)));
      *(bf16x8*)(P.henc + ((size_t)tx*512 + b0 + row)*512 + (cell==3?256:0) + dim0 + dgrp) = hv;
    }
    lds_barrier();
    p ^= 1; q ^= 1;
  }
  #pragma unroll
  for(int jt=0;jt<2;jt++)
    #pragma unroll
    for(int rr=0;rr<4;rr++)
      P.hcar[((size_t)cell*512 + b0 + lq*4+rr)*256 + dim0 + jt*16 + lr] = hold[jt][rr];
}

// ---------------- K3: g0 head ----------------
__global__ void g0_kernel(const float* __restrict__ hgf, const float* __restrict__ hgb,
                          const float* __restrict__ Wm, const float* __restrict__ bm,
                          const float* __restrict__ Wv, const float* __restrict__ bv,
                          const float* __restrict__ eps,
                          float* __restrict__ o_mean, float* __restrict__ o_logv,
                          float* __restrict__ g0){
  int j = blockIdx.x*blockDim.x + threadIdx.x;    // 512*256
  int b = j>>8, d = j&255;
  const float4* hf=(const float4*)(hgf + (size_t)b*256);
  const float4* hb=(const float4*)(hgb + (size_t)b*256);
  const float4* mp=(const float4*)(Wm + (size_t)d*512);
  const float4* vp=(const float4*)(Wv + (size_t)d*512);
  float am=0.f, av=0.f;
  #pragma unroll 4
  for(int k=0;k<64;k++){
    float4 h=hf[k], m=mp[k], v=vp[k];
    am += h.x*m.x + h.y*m.y + h.z*m.z + h.w*m.w;
    av += h.x*v.x + h.y*v.y + h.z*v.z + h.w*v.w;
  }
  #pragma unroll 4
  for(int k=0;k<64;k++){
    float4 h=hb[k], m=mp[64+k], v=vp[64+k];
    am += h.x*m.x + h.y*m.y + h.z*m.z + h.w*m.w;
    av += h.x*v.x + h.y*v.y + h.z*v.z + h.w*v.w;
  }
  float mean = am + bm[d];
  float ev   = __expf(av + bv[d]) + 1e-4f;
  float lv   = __logf(ev);
  o_mean[j]=mean; o_logv[j]=lv;
  g0[j] = eps[j]*sqrtf(ev) + mean;
}

// ---------------- K4: gictT[t][384][512] = (h_enc_c @ Wct[:,:512]^T)^T ----------------
__global__ __launch_bounds__(256,2) void gict_gemm(const __bf16* __restrict__ henc,
                                                   const __bf16* __restrict__ wct,   // [384][576]
                                                   __bf16* __restrict__ gictT){
  const int tid=threadIdx.x, w=tid>>6, l=tid&63, lr=l&15, lq=l>>4;
  const int m0 = blockIdx.x*8 + w*2;
  bf16x8 a[2][16];
  #pragma unroll
  for(int m=0;m<2;m++){
    const __bf16* ap = henc + (size_t)((m0+m)*16 + lr)*512 + lq*8;
    #pragma unroll
    for(int kt=0;kt<16;kt++) a[m][kt] = *(const bf16x8*)(ap + kt*32);
  }
  #pragma unroll 1
  for(int nt=0;nt<24;nt++){
    f32x4 c0={}, c1={};
    const __bf16* bp = wct + (size_t)(nt*16+lr)*576 + lq*8;
    #pragma unroll
    for(int kt=0;kt<16;kt++){
      bf16x8 bb = *(const bf16x8*)(bp + kt*32);
      c0 = MFMA_B16(a[0][kt], bb, c0);
      c1 = MFMA_B16(a[1][kt], bb, c1);
    }
    #pragma unroll
    for(int m=0;m<2;m++){
      f32x4 c = m? c1 : c0;
      int R0 = (m0+m)*16 + lq*4;
      int t  = R0>>9, b = R0&511;
      bf16x4 pk;
      pk[0]=(__bf16)c[0]; pk[1]=(__bf16)c[1]; pk[2]=(__bf16)c[2]; pk[3]=(__bf16)c[3];
      *(bf16x4*)(gictT + ((size_t)t*384 + nt*16+lr)*512 + b) = pk;
    }
  }
}

// ---------------- K5: generator scan ----------------
// 32 blocks x 8 waves; whh_gn r,z pinned in 128 VGPRs; wih_gn in LDS; rest streamed L2.
struct GenP{
  const __bf16 *wct, *whh_ct, *wih_gn, *whh_gn, *w_um, *w_uv, *w_f;
  const float  *bih_ct, *bhh_ct, *bih_gn, *bhh_gn, *b_um, *b_uv, *b_f;
  const __bf16* gihT;   // [200][384][512]
  const float*  g0;     // [512][256]
  const float*  eps_u;  // [512][200][64]
  float *o_um, *o_ul, *o_f;
};
__global__ __launch_bounds__(512,2) void gen_scan(GenP P){
  const int tid=threadIdx.x, w=tid>>6, l=tid&63, lr=l&15, lq=l>>4;
  const int b0 = blockIdx.x*16;

  __shared__ __align__(16) __bf16 wgnL[768*64];      // 96KB, swizzled (stride 128B)
  __shared__ __align__(16) __bf16 hcA[2][16*128];    // 2 x 4KB
  __shared__ __align__(16) __bf16 gA [2][16*256];    // 2 x 8KB
  __shared__ __align__(16) __bf16 uA [16*64];        // 2KB
  __shared__ __align__(16) __bf16 fA [16*64];        // 2KB

  // stage wih_gn into swizzled LDS
  for(int c=tid; c<6144; c+=512){
    int row = c>>3, part = c&7;
    bf16x8 v = *(const bf16x8*)(P.wih_gn + (size_t)row*64 + part*8);
    *(bf16x8*)((char*)wgnL + ((row*128 + part*16) ^ ((row&7)<<4))) = v;
  }
  // persistent r,z gates of whh_gn (128 VGPRs)
  bf16x8 wrz[2][2][8];
  #pragma unroll
  for(int jt=0;jt<2;jt++)
    #pragma unroll
    for(int g=0;g<2;g++)
      #pragma unroll
      for(int kt=0;kt<8;kt++)
        wrz[jt][g][kt] = *(const bf16x8*)(P.whh_gn + (size_t)(g*256 + w*32 + jt*16 + lr)*256 + kt*32 + lq*8);

  const int dct = w*16 + lr;          // ct dim owned (all 8 waves)
  const int du  = (w&3)*16 + lr;      // u/f dim (waves 0-3)
  // biases
  const float bctR = P.bih_ct[dct]     + P.bhh_ct[dct];
  const float bctZ = P.bih_ct[128+dct] + P.bhh_ct[128+dct];
  const float bctI = P.bih_ct[256+dct];
  const float bctH = P.bhh_ct[256+dct];
  float bgnR[2], bgnZ[2], bgnI[2], bgnH[2];
  #pragma unroll
  for(int jt=0;jt<2;jt++){
    int d = w*32 + jt*16 + lr;
    bgnR[jt] = P.bih_gn[d]     + P.bhh_gn[d];
    bgnZ[jt] = P.bih_gn[256+d] + P.bhh_gn[256+d];
    bgnI[jt] = P.bih_gn[512+d];
    bgnH[jt] = P.bhh_gn[512+d];
  }
  const float bum = P.b_um[du], buv = P.b_uv[du], bff = P.b_f[du];

  // carries + init
  f32x4 gC[2], hcC;
  hcC = (f32x4){};
  #pragma unroll
  for(int jt=0;jt<2;jt++)
    #pragma unroll
    for(int rr=0;rr<4;rr++){
      float v = P.g0[(size_t)(b0+lq*4+rr)*256 + w*32 + jt*16 + lr];
      gC[jt][rr] = v;
      lds_wr(gA[0], lq*4+rr, w*32+jt*16+lr, 512, v);
    }
  for(int i=tid;i<16*128;i+=512) hcA[0][i] = (__bf16)0.f;
  __syncthreads();
  // f0 = g0 @ W_f^T + b_f (waves 0-3)
  if(w<4){
    f32x4 fa={};
    #pragma unroll
    for(int kt=0;kt<8;kt++){
      bf16x8 gf = lds_rdA(gA[0], lr, kt, lq, 512);
      fa = MFMA_B16(gf, *(const bf16x8*)(P.w_f + (size_t)du*256 + kt*32 + lq*8), fa);
    }
    #pragma unroll
    for(int rr=0;rr<4;rr++) lds_wr(fA, lq*4+rr, du, 128, fa[rr]+bff);
  }
  // prefetch gihT(0) + eps(0)
  ushort4 gpR, gpZ, gpN; float epf[4];
  gpR = *(const ushort4*)(P.gihT + ((size_t)0*384 +       dct)*512 + b0 + lq*4);
  gpZ = *(const ushort4*)(P.gihT + ((size_t)0*384 + 128 + dct)*512 + b0 + lq*4);
  gpN = *(const ushort4*)(P.gihT + ((size_t)0*384 + 256 + dct)*512 + b0 + lq*4);
  if(w<4){
    #pragma unroll
    for(int rr=0;rr<4;rr++) epf[rr] = P.eps_u[((size_t)(b0+lq*4+rr)*TT + 0)*64 + du];
  }
  __syncthreads();

  int pc=0, pg=0;
  #pragma unroll 1
  for(int t=0;t<TT;t++){
    // ---------- P1: controller GRU ----------
    {
      bf16x8 ff0 = lds_rdA(fA, lr, 0, lq, 128);
      bf16x8 ff1 = lds_rdA(fA, lr, 1, lq, 128);
      bf16x8 hp0 = lds_rdA(hcA[pc], lr, 0, lq, 256);
      bf16x8 hp1 = lds_rdA(hcA[pc], lr, 1, lq, 256);
      bf16x8 hp2 = lds_rdA(hcA[pc], lr, 2, lq, 256);
      bf16x8 hp3 = lds_rdA(hcA[pc], lr, 3, lq, 256);
      f32x4 aR={}, aZ={}, aI={}, aH={};
      #pragma unroll
      for(int g=0;g<3;g++){
        const __bf16* wif = P.wct    + (size_t)(g*128+dct)*576 + 512 + lq*8;
        const __bf16* whc = P.whh_ct + (size_t)(g*128+dct)*128 + lq*8;
        bf16x8 wf0 = *(const bf16x8*)(wif);
        bf16x8 wf1 = *(const bf16x8*)(wif + 32);
        bf16x8 wh0 = *(const bf16x8*)(whc);
        bf16x8 wh1 = *(const bf16x8*)(whc + 32);
        bf16x8 wh2 = *(const bf16x8*)(whc + 64);
        bf16x8 wh3 = *(const bf16x8*)(whc + 96);
        if(g==0){
          aR = MFMA_B16(ff0,wf0,aR); aR = MFMA_B16(ff1,wf1,aR);
          aR = MFMA_B16(hp0,wh0,aR); aR = MFMA_B16(hp1,wh1,aR);
          aR = MFMA_B16(hp2,wh2,aR); aR = MFMA_B16(hp3,wh3,aR);
        }else if(g==1){
          aZ = MFMA_B16(ff0,wf0,aZ); aZ = MFMA_B16(ff1,wf1,aZ);
          aZ = MFMA_B16(hp0,wh0,aZ); aZ = MFMA_B16(hp1,wh1,aZ);
          aZ = MFMA_B16(hp2,wh2,aZ); aZ = MFMA_B16(hp3,wh3,aZ);
        }else{
          aI = MFMA_B16(ff0,wf0,aI); aI = MFMA_B16(ff1,wf1,aI);
          aH = MFMA_B16(hp0,wh0,aH); aH = MFMA_B16(hp1,wh1,aH);
          aH = MFMA_B16(hp2,wh2,aH); aH = MFMA_B16(hp3,wh3,aH);
        }
      }
      const unsigned short* uR=(const unsigned short*)&gpR;
      const unsigned short* uZ=(const unsigned short*)&gpZ;
      const unsigned short* uN=(const unsigned short*)&gpN;
      #pragma unroll
      for(int rr=0;rr<4;rr++){
        float r = sig_f(aR[rr] + bf2f(uR[rr]) + bctR);
        float z = sig_f(aZ[rr] + bf2f(uZ[rr]) + bctZ);
        float nn= tanh_f(aI[rr] + bf2f(uN[rr]) + bctI + r*(aH[rr] + bctH));
        float h = (1.f-z)*nn + z*hcC[rr];
        h = fminf(fmaxf(h,0.f), 5.f);
        hcC[rr] = h;
        lds_wr(hcA[1-pc], lq*4+rr, dct, 256, h);
      }
    }
    lds_barrier();

    // ---------- P2: um/uv + sample (waves 0-3) ----------
    if(w<4){
      bf16x8 hn0 = lds_rdA(hcA[1-pc], lr, 0, lq, 256);
      bf16x8 hn1 = lds_rdA(hcA[1-pc], lr, 1, lq, 256);
      bf16x8 hn2 = lds_rdA(hcA[1-pc], lr, 2, lq, 256);
      bf16x8 hn3 = lds_rdA(hcA[1-pc], lr, 3, lq, 256);
      f32x4 am={}, av={};
      const __bf16* wm = P.w_um + (size_t)du*128 + lq*8;
      const __bf16* wv = P.w_uv + (size_t)du*128 + lq*8;
      am = MFMA_B16(hn0, *(const bf16x8*)(wm   ), am);
      am = MFMA_B16(hn1, *(const bf16x8*)(wm+32), am);
      am = MFMA_B16(hn2, *(const bf16x8*)(wm+64), am);
      am = MFMA_B16(hn3, *(const bf16x8*)(wm+96), am);
      av = MFMA_B16(hn0, *(const bf16x8*)(wv   ), av);
      av = MFMA_B16(hn1, *(const bf16x8*)(wv+32), av);
      av = MFMA_B16(hn2, *(const bf16x8*)(wv+64), av);
      av = MFMA_B16(hn3, *(const bf16x8*)(wv+96), av);
      #pragma unroll
      for(int rr=0;rr<4;rr++){
        const int row = lq*4+rr;
        float um = am[rr] + bum;
        float ul = av[rr] + buv;
        size_t oi = ((size_t)(b0+row)*TT + t)*64 + du;
        P.o_um[oi] = um;
        P.o_ul[oi] = ul;
        float u = epf[rr]*__expf(0.5f*ul) + um;
        lds_wr(uA, row, du, 128, u);
      }
    }
    lds_barrier();

    // ---------- P3: generator GRU ----------
    {
      // prefetch gihT/eps for t+1 (in flight across barriers)
      const int tn = (t+1<TT)? t+1 : TT-1;
      gpR = *(const ushort4*)(P.gihT + ((size_t)tn*384 +       dct)*512 + b0 + lq*4);
      gpZ = *(const ushort4*)(P.gihT + ((size_t)tn*384 + 128 + dct)*512 + b0 + lq*4);
      gpN = *(const ushort4*)(P.gihT + ((size_t)tn*384 + 256 + dct)*512 + b0 + lq*4);
      if(w<4){
        #pragma unroll
        for(int rr=0;rr<4;rr++) epf[rr] = P.eps_u[((size_t)(b0+lq*4+rr)*TT + tn)*64 + du];
      }
      bf16x8 uf0 = lds_rdA(uA, lr, 0, lq, 128);
      bf16x8 uf1 = lds_rdA(uA, lr, 1, lq, 128);
      #pragma unroll
      for(int jt=0;jt<2;jt++){
        const int dg = w*32 + jt*16 + lr;
        // streamed n-gate of whh_gn
        bf16x8 wn[8];
        #pragma unroll
        for(int kt=0;kt<8;kt++)
          wn[kt] = *(const bf16x8*)(P.whh_gn + (size_t)(512 + dg)*256 + kt*32 + lq*8);
        f32x4 aR={}, aZ={}, aI={}, aH={};
        // u-part from LDS wih_gn (swizzled, stride 128)
        #pragma unroll
        for(int g=0;g<3;g++){
          const int row = g*256 + dg;
          bf16x8 w0 = *(const bf16x8*)((const char*)wgnL + ((row*128 +  0 + lq*16) ^ ((row&7)<<4)));
          bf16x8 w1 = *(const bf16x8*)((const char*)wgnL + ((row*128 + 64 + lq*16) ^ ((row&7)<<4)));
          if(g==0){ aR = MFMA_B16(uf0,w0,aR); aR = MFMA_B16(uf1,w1,aR); }
          else if(g==1){ aZ = MFMA_B16(uf0,w0,aZ); aZ = MFMA_B16(uf1,w1,aZ); }
          else { aI = MFMA_B16(uf0,w0,aI); aI = MFMA_B16(uf1,w1,aI); }
        }
        // g-part: r,z from registers, n streamed
        #pragma unroll
        for(int kt=0;kt<8;kt++){
          bf16x8 gf = lds_rdA(gA[pg], lr, kt, lq, 512);
          aR = MFMA_B16(gf, wrz[jt][0][kt], aR);
          aZ = MFMA_B16(gf, wrz[jt][1][kt], aZ);
          aH = MFMA_B16(gf, wn[kt], aH);
        }
        #pragma unroll
        for(int rr=0;rr<4;rr++){
          float r = sig_f(aR[rr] + bgnR[jt]);
          float z = sig_f(aZ[rr] + bgnZ[jt]);
          float nn= tanh_f(aI[rr] + bgnI[jt] + r*(aH[rr] + bgnH[jt]));
          float gv = (1.f-z)*nn + z*gC[jt][rr];
          gv = fminf(fmaxf(gv,0.f), 5.f);
          gC[jt][rr] = gv;
          lds_wr(gA[1-pg], lq*4+rr, dg, 512, gv);
        }
      }
    }
    lds_barrier();

    // ---------- P4: f = g @ W_f^T + b_f (waves 0-3) ----------
    if(w<4){
      f32x4 fa={};
      const __bf16* wfp = P.w_f + (size_t)du*256 + lq*8;
      #pragma unroll
      for(int kt=0;kt<8;kt++){
        bf16x8 gf = lds_rdA(gA[1-pg], lr, kt, lq, 512);
        fa = MFMA_B16(gf, *(const bf16x8*)(wfp + kt*32), fa);
      }
      #pragma unroll
      for(int rr=0;rr<4;rr++){
        const int row = lq*4+rr;
        float v = fa[rr] + bff;
        P.o_f[((size_t)(b0+row)*TT + t)*64 + du] = v;
        lds_wr(fA, row, du, 128, v);
      }
    }
    lds_barrier();
    pc ^= 1; pg ^= 1;
  }
}

// ---------------- K6: rates ----------------
__global__ void rates_k(const float* __restrict__ fac, const float* __restrict__ Wr,
                        const float* __restrict__ br, float* __restrict__ out){
  const int total = 512*200*256;
  int i = blockIdx.x*blockDim.x + threadIdx.x;
  int st = gridDim.x*blockDim.x;
  for(; i<total; i+=st){
    int row = i>>8, n = i&255;
    const float4* fp=(const float4*)(fac + (size_t)row*64);
    const float4* wp=(const float4*)(Wr  + (size_t)n*64);
    float a = 0.f;
    #pragma unroll
    for(int k=0;k<16;k++){
      float4 f=fp[k], ww=wp[k];
      a += f.x*ww.x + f.y*ww.y + f.z*ww.z + f.w*ww.w;
    }
    a += br[n];
    a = fminf(fmaxf(a, -5.f), 5.f);
    out[i] = __expf(a);
  }
}

// ---------------- host ----------------
extern "C" void kernel_launch(void* const* d_in, const int* in_sizes, int n_in,
                              void* d_out, int out_size, void* d_ws, size_t ws_size,
                              hipStream_t stream){
  (void)in_sizes; (void)n_in; (void)out_size; (void)ws_size;
  const float* x      = (const float*)d_in[0];
  const float* eps_g0 = (const float*)d_in[1];
  const float* eps_u  = (const float*)d_in[2];
  const float* Wih_f[6]; const float* Whh_f[6]; const float* bih[6]; const float* bhh[6];
  for(int c=0;c<6;c++){
    Wih_f[c]=(const float*)d_in[3+4*c]; Whh_f[c]=(const float*)d_in[4+4*c];
    bih[c]  =(const float*)d_in[5+4*c]; bhh[c]  =(const float*)d_in[6+4*c];
  }
  const float* W_g0m=(const float*)d_in[27]; const float* b_g0m=(const float*)d_in[28];
  const float* W_g0v=(const float*)d_in[29]; const float* b_g0v=(const float*)d_in[30];
  const float* W_um =(const float*)d_in[31]; const float* b_um =(const float*)d_in[32];
  const float* W_uv =(const float*)d_in[33]; const float* b_uv =(const float*)d_in[34];
  const float* W_f  =(const float*)d_in[35]; const float* b_f  =(const float*)d_in[36];
  const float* W_r  =(const float*)d_in[37]; const float* b_r  =(const float*)d_in[38];

  char* ws = (char*)d_ws; size_t off = 0;
  auto alloc = [&](size_t bytes)->char*{
    char* p = ws + off; off = (off + bytes + 255) & ~(size_t)255; return p;
  };
  __bf16* wencall = (__bf16*)alloc((size_t)4*768*256*2);  // 4 cells' Wih stacked
  __bf16* whhall  = (__bf16*)alloc((size_t)4*768*256*2);
  __bf16* wct_b   = (__bf16*)alloc((size_t)384*576*2);
  __bf16* whhct_b = (__bf16*)alloc((size_t)384*128*2);
  __bf16* wihgn_b = (__bf16*)alloc((size_t)768*64*2);
  __bf16* whhgn_b = (__bf16*)alloc((size_t)768*256*2);
  __bf16* wum_b   = (__bf16*)alloc((size_t)64*128*2);
  __bf16* wuv_b   = (__bf16*)alloc((size_t)64*128*2);
  __bf16* wf_b    = (__bf16*)alloc((size_t)64*256*2);
  __bf16* henc    = (__bf16*)alloc((size_t)200*512*512*2);      // 105MB
  __bf16* gi_buf  = (__bf16*)alloc((size_t)4*TC*768*512*2);     // 78.6MB (reused as gictT)
  float*  hcar    = (float*)alloc((size_t)4*512*256*4);
  float*  g0buf   = (float*)alloc((size_t)512*256*4);

  // weight conversions
  for(int c=0;c<4;c++){
    cvt_bf16<<<128,256,0,stream>>>(Wih_f[c], wencall + (size_t)c*768*256, 768*256);
    cvt_bf16<<<128,256,0,stream>>>(Whh_f[c], whhall  + (size_t)c*768*256, 768*256);
  }
  cvt_bf16<<<128,256,0,stream>>>(Wih_f[4], wct_b,   384*576);
  cvt_bf16<<<64 ,256,0,stream>>>(Whh_f[4], whhct_b, 384*128);
  cvt_bf16<<<64 ,256,0,stream>>>(Wih_f[5], wihgn_b, 768*64);
  cvt_bf16<<<128,256,0,stream>>>(Whh_f[5], whhgn_b, 768*256);
  cvt_bf16<<<32 ,256,0,stream>>>(W_um, wum_b, 64*128);
  cvt_bf16<<<32 ,256,0,stream>>>(W_uv, wuv_b, 64*128);
  cvt_bf16<<<32 ,256,0,stream>>>(W_f,  wf_b,  64*256);
  hipMemsetAsync(hcar, 0, (size_t)4*512*256*4, stream);

  // encoder: chunked gi GEMM + persistent scan
  EncP ep;
  ep.whh = whhall;
  for(int c=0;c<4;c++){ ep.bih[c]=bih[c]; ep.bhh[c]=bhh[c]; }
  ep.gi = gi_buf; ep.henc = henc; ep.hcar = hcar;
  for(int k=0;k<NCH;k++){
    gi_gemm<<<dim3((512*TC)/64,4),256,0,stream>>>(x, wencall, gi_buf, k*TC);
    ep.t0 = k*TC;
    enc_scan<<<dim3(32,4),512,0,stream>>>(ep);
  }

  float* out = (float*)d_out;
  float* o_mean = out;
  float* o_logv = out + 131072;
  float* o_um   = out + 262144;
  float* o_ul   = out + 6815744;
  float* o_f    = out + 13369344;
  float* o_r    = out + 19922944;

  g0_kernel<<<512,256,0,stream>>>(hcar + 0, hcar + (size_t)1*512*256,
                                  W_g0m,b_g0m, W_g0v,b_g0v, eps_g0,
                                  o_mean,o_logv, g0buf);
  // gictT reuses gi_buf
  gict_gemm<<<800,256,0,stream>>>(henc, wct_b, gi_buf);

  GenP gp;
  gp.wct=wct_b; gp.whh_ct=whhct_b; gp.wih_gn=wihgn_b; gp.whh_gn=whhgn_b;
  gp.w_um=wum_b; gp.w_uv=wuv_b; gp.w_f=wf_b;
  gp.bih_ct=bih[4]; gp.bhh_ct=bhh[4]; gp.bih_gn=bih[5]; gp.bhh_gn=bhh[5];
  gp.b_um=b_um; gp.b_uv=b_uv; gp.b_f=b_f;
  gp.gihT=gi_buf; gp.g0=g0buf; gp.eps_u=eps_u;
  gp.o_um=o_um; gp.o_ul=o_ul; gp.o_f=o_f;
  gen_scan<<<32,512,0,stream>>>(gp);

  rates_k<<<8192,256,0,stream>>>(o_f, W_r, b_r, o_r);
}